// Round 1
// baseline (2225.338 us; speedup 1.0000x reference)
//
#include <hip/hip_runtime.h>
#include <hip/hip_bf16.h>
#include <math.h>

// BernNet forward: h = relu(x@W1+b1)@W2+b2 ; out = sum_m c_m A^m h ; log_softmax
// where c_m derived on-device from TEMP=relu(temp):
//   out = (1/2^K) sum_j C(K,j) TEMP[j] (I-A)^j (I+A)^{K-j} h  (polynomial in A)
// A = D^-1/2-weighted adjacency scattered by dst (deg from src), CSR built per launch.

#define NFEAT 512
#define HIDDEN 128
#define NCLASS 64
#define KORD 10

// ---------------- degree / CSR build ----------------

__global__ void k_deg(const int* __restrict__ src, float* __restrict__ deg, int E) {
    int e = blockIdx.x * blockDim.x + threadIdx.x;
    if (e < E) atomicAdd(&deg[src[e]], 1.0f);
}

__global__ void k_dinv(float* __restrict__ deg, int N) {
    int i = blockIdx.x * blockDim.x + threadIdx.x;
    if (i < N) {
        float d = deg[i];
        deg[i] = (d > 0.0f) ? rsqrtf(d) : 0.0f;
    }
}

__global__ void k_count(const int* __restrict__ dst, int* __restrict__ cnt, int E) {
    int e = blockIdx.x * blockDim.x + threadIdx.x;
    if (e < E) atomicAdd(&cnt[dst[e]], 1);
}

// single-block exclusive scan of cnt[0..n) -> row_ptr[0..n], row_ptr[n]=total
__global__ __launch_bounds__(1024) void k_scan(const int* __restrict__ cnt,
                                               int* __restrict__ row_ptr, int n) {
    __shared__ int s[1024];
    __shared__ int carry;
    if (threadIdx.x == 0) carry = 0;
    __syncthreads();
    for (int base = 0; base < n; base += 1024) {
        int i = base + threadIdx.x;
        int val = (i < n) ? cnt[i] : 0;
        s[threadIdx.x] = val;
        __syncthreads();
        #pragma unroll
        for (int off = 1; off < 1024; off <<= 1) {
            int t = (threadIdx.x >= (unsigned)off) ? s[threadIdx.x - off] : 0;
            __syncthreads();
            s[threadIdx.x] += t;
            __syncthreads();
        }
        int incl = s[threadIdx.x];
        if (i < n) row_ptr[i] = carry + incl - val;
        __syncthreads();
        if (threadIdx.x == 1023) carry += incl;
        __syncthreads();
    }
    if (threadIdx.x == 0) row_ptr[n] = carry;
}

__global__ void k_pos(const int* __restrict__ row_ptr, int* __restrict__ pos, int N) {
    int i = blockIdx.x * blockDim.x + threadIdx.x;
    if (i < N) pos[i] = row_ptr[i];
}

__global__ void k_fill(const int* __restrict__ src, const int* __restrict__ dst,
                       const float* __restrict__ dinv, int* __restrict__ pos,
                       int2* __restrict__ csr, int E) {
    int e = blockIdx.x * blockDim.x + threadIdx.x;
    if (e < E) {
        int s = src[e], d = dst[e];
        int idx = atomicAdd(&pos[d], 1);
        float w = dinv[s] * dinv[d];
        csr[idx] = make_int2(s, __float_as_int(w));
    }
}

// ---------------- Bernstein coefficients ----------------
// c[m] = (1/2^K) sum_j C(K,j) T[j] * [a^m]( (1-a)^j (1+a)^{K-j} )
__global__ void k_coef(const float* __restrict__ temp, float* __restrict__ c,
                       float* __restrict__ temp_out) {
    if (threadIdx.x != 0 || blockIdx.x != 0) return;
    float T[KORD + 1];
    #pragma unroll
    for (int j = 0; j <= KORD; ++j) {
        T[j] = fmaxf(temp[j], 0.0f);
        temp_out[j] = T[j];
    }
    float binom[KORD + 1][KORD + 1];
    for (int n = 0; n <= KORD; ++n) {
        binom[n][0] = 1.0f;
        for (int k = 1; k <= n; ++k)
            binom[n][k] = (k == n) ? 1.0f : binom[n - 1][k - 1] + binom[n - 1][k];
        for (int k = n + 1; k <= KORD; ++k) binom[n][k] = 0.0f;
    }
    for (int m = 0; m <= KORD; ++m) {
        float s = 0.0f;
        for (int j = 0; j <= KORD; ++j) {
            float cj = 0.0f;
            for (int p = 0; p <= j && p <= m; ++p) {
                int q = m - p;
                if (q > KORD - j) continue;
                float t = binom[j][p] * binom[KORD - j][q];
                cj += (p & 1) ? -t : t;
            }
            s += binom[KORD][j] * T[j] * cj;
        }
        c[m] = s * (1.0f / 1024.0f);
    }
}

// ---------------- tiled fp32 GEMM with bias (+optional relu), N == BN ----------------

template <int BM, int BN, int BK, int TM, int TN, bool RELU>
__global__ __launch_bounds__(256) void gemm_bias(const float* __restrict__ A,
                                                 const float* __restrict__ B,
                                                 const float* __restrict__ bias,
                                                 float* __restrict__ C, int M, int K) {
    __shared__ float As[BM][BK + 4];
    __shared__ float Bs[BK][BN];
    const int tid = threadIdx.x;
    const int tx = tid & 15;
    const int ty = tid >> 4;
    const int m0 = blockIdx.x * BM;

    float acc[TM][TN];
    #pragma unroll
    for (int i = 0; i < TM; ++i)
        #pragma unroll
        for (int j = 0; j < TN; ++j) acc[i][j] = 0.0f;

    for (int k0 = 0; k0 < K; k0 += BK) {
        #pragma unroll
        for (int i = tid * 4; i < BM * BK; i += 256 * 4) {
            int r = i / BK, cc = i % BK;
            float4 v = make_float4(0.f, 0.f, 0.f, 0.f);
            if (m0 + r < M) v = *(const float4*)&A[(size_t)(m0 + r) * K + k0 + cc];
            *(float4*)&As[r][cc] = v;
        }
        #pragma unroll
        for (int i = tid * 4; i < BK * BN; i += 256 * 4) {
            int r = i / BN, cc = i % BN;
            *(float4*)&Bs[r][cc] = *(const float4*)&B[(size_t)(k0 + r) * BN + cc];
        }
        __syncthreads();
        #pragma unroll
        for (int kk = 0; kk < BK; ++kk) {
            float a[TM], b[TN];
            #pragma unroll
            for (int i = 0; i < TM; ++i) a[i] = As[ty * TM + i][kk];
            #pragma unroll
            for (int j = 0; j < TN; j += 4)
                *(float4*)&b[j] = *(const float4*)&Bs[kk][tx * TN + j];
            #pragma unroll
            for (int i = 0; i < TM; ++i)
                #pragma unroll
                for (int j = 0; j < TN; ++j) acc[i][j] += a[i] * b[j];
        }
        __syncthreads();
    }

    #pragma unroll
    for (int i = 0; i < TM; ++i) {
        int r = m0 + ty * TM + i;
        if (r < M) {
            #pragma unroll
            for (int j = 0; j < TN; j += 4) {
                float4 v;
                float* vp = &v.x;
                #pragma unroll
                for (int q = 0; q < 4; ++q) {
                    float z = acc[i][j + q] + bias[tx * TN + j + q];
                    if (RELU) z = fmaxf(z, 0.0f);
                    vp[q] = z;
                }
                *(float4*)&C[(size_t)r * BN + tx * TN + j] = v;
            }
        }
    }
}

// ---------------- out = c0 * h (also initializes d_out region) ----------------

__global__ void k_init_out(const float4* __restrict__ h, float4* __restrict__ out,
                           const float* __restrict__ c, int n4) {
    int i = blockIdx.x * blockDim.x + threadIdx.x;
    if (i < n4) {
        float c0 = c[0];
        float4 v = h[i];
        out[i] = make_float4(c0 * v.x, c0 * v.y, c0 * v.z, c0 * v.w);
    }
}

// ---------------- SpMV: vout = A vin ; out += c[m] * vout ----------------
// one wave per node, lane = feature

__global__ __launch_bounds__(256) void k_adj(const float* __restrict__ vin,
                                             float* __restrict__ vout,
                                             const int* __restrict__ row_ptr,
                                             const int2* __restrict__ csr,
                                             float* __restrict__ out,
                                             const float* __restrict__ c, int m, int N) {
    int wid = blockIdx.x * (blockDim.x >> 6) + (threadIdx.x >> 6);
    int lane = threadIdx.x & 63;
    if (wid >= N) return;
    int b = row_ptr[wid], e2 = row_ptr[wid + 1];
    float a0 = 0.f, a1 = 0.f, a2 = 0.f, a3 = 0.f;
    int i = b;
    for (; i + 3 < e2; i += 4) {
        int2 p0 = csr[i], p1 = csr[i + 1], p2 = csr[i + 2], p3 = csr[i + 3];
        a0 += __int_as_float(p0.y) * vin[p0.x * 64 + lane];
        a1 += __int_as_float(p1.y) * vin[p1.x * 64 + lane];
        a2 += __int_as_float(p2.y) * vin[p2.x * 64 + lane];
        a3 += __int_as_float(p3.y) * vin[p3.x * 64 + lane];
    }
    for (; i < e2; ++i) {
        int2 p = csr[i];
        a0 += __int_as_float(p.y) * vin[p.x * 64 + lane];
    }
    float acc = (a0 + a1) + (a2 + a3);
    int o = wid * 64 + lane;
    vout[o] = acc;
    out[o] += c[m] * acc;
}

// ---------------- log_softmax over rows of 64 ----------------

__global__ __launch_bounds__(256) void k_logsm(float* __restrict__ out, int N) {
    int wid = blockIdx.x * (blockDim.x >> 6) + (threadIdx.x >> 6);
    int lane = threadIdx.x & 63;
    if (wid >= N) return;
    float val = out[wid * 64 + lane];
    float mx = val;
    #pragma unroll
    for (int off = 32; off >= 1; off >>= 1) mx = fmaxf(mx, __shfl_xor(mx, off));
    float e = __expf(val - mx);
    float s = e;
    #pragma unroll
    for (int off = 32; off >= 1; off >>= 1) s += __shfl_xor(s, off);
    out[wid * 64 + lane] = val - mx - __logf(s);
}

// ---------------- launch ----------------

extern "C" void kernel_launch(void* const* d_in, const int* in_sizes, int n_in,
                              void* d_out, int out_size, void* d_ws, size_t ws_size,
                              hipStream_t stream) {
    const float* x = (const float*)d_in[0];
    const int* ei = (const int*)d_in[1];
    const float* W1 = (const float*)d_in[2];
    const float* b1 = (const float*)d_in[3];
    const float* W2 = (const float*)d_in[4];
    const float* b2 = (const float*)d_in[5];
    const float* temp = (const float*)d_in[6];

    const int N = in_sizes[0] / NFEAT;   // 100000
    const int E = in_sizes[1] / 2;       // 3200000
    const int* src = ei;
    const int* dst = ei + E;

    float* out = (float*)d_out;                 // [N*64] logits then log_softmax
    float* temp_out = out + (size_t)N * NCLASS; // [11]

    // workspace carve-up (256B aligned)
    char* ws = (char*)d_ws;
    size_t off = 0;
    auto alloc = [&](size_t bytes) {
        char* p = ws + off;
        off = (off + bytes + 255) & ~(size_t)255;
        return p;
    };
    float* h1 = (float*)alloc((size_t)N * HIDDEN * sizeof(float));
    float* h = (float*)alloc((size_t)N * NCLASS * sizeof(float));
    float* v1 = (float*)alloc((size_t)N * NCLASS * sizeof(float));
    float* v2 = (float*)alloc((size_t)N * NCLASS * sizeof(float));
    float* deg = (float*)alloc((size_t)N * sizeof(float));     // becomes dinv
    int* cnt = (int*)alloc((size_t)N * sizeof(int));
    int* row_ptr = (int*)alloc((size_t)(N + 1) * sizeof(int));
    int* pos = (int*)alloc((size_t)N * sizeof(int));
    int2* csr = (int2*)alloc((size_t)E * sizeof(int2));
    float* c = (float*)alloc(64);
    (void)ws_size;

    const int TB = 256;
    const int egrid = (E + TB - 1) / TB;
    const int ngrid = (N + TB - 1) / TB;
    const int wgrid = (N + 3) / 4;  // 4 waves per 256-block, 1 wave/node

    // degree + CSR build (per launch; ws not re-poisoned between replays)
    hipMemsetAsync(deg, 0, (size_t)N * sizeof(float), stream);
    hipMemsetAsync(cnt, 0, (size_t)N * sizeof(int), stream);
    k_deg<<<egrid, TB, 0, stream>>>(src, deg, E);
    k_dinv<<<ngrid, TB, 0, stream>>>(deg, N);
    k_count<<<egrid, TB, 0, stream>>>(dst, cnt, E);
    k_scan<<<1, 1024, 0, stream>>>(cnt, row_ptr, N);
    k_pos<<<ngrid, TB, 0, stream>>>(row_ptr, pos, N);
    k_fill<<<egrid, TB, 0, stream>>>(src, dst, deg, pos, csr, E);

    // Bernstein coefficients + TEMP output
    k_coef<<<1, 64, 0, stream>>>(temp, c, temp_out);

    // MLP
    const int mgrid = (N + 63) / 64;
    gemm_bias<64, HIDDEN, 32, 4, 8, true><<<mgrid, 256, 0, stream>>>(x, W1, b1, h1, N, NFEAT);
    gemm_bias<64, NCLASS, 32, 4, 4, false><<<mgrid, 256, 0, stream>>>(h1, W2, b2, h, N, HIDDEN);

    // out = c0*h ; then out += c_m * A^m h for m=1..K
    const int n4 = N * NCLASS / 4;
    k_init_out<<<(n4 + TB - 1) / TB, TB, 0, stream>>>((const float4*)h, (float4*)out, c, n4);

    const float* vin = h;
    float* va = v1;
    float* vb = v2;
    for (int m = 1; m <= KORD; ++m) {
        k_adj<<<wgrid, TB, 0, stream>>>(vin, va, row_ptr, csr, out, c, m, N);
        vin = va;
        float* t = va; va = vb; vb = t;
        if (m == 1) vb = v1;  // after first step, ping-pong v1/v2
    }

    k_logsm<<<wgrid, TB, 0, stream>>>(out, N);
}

// Round 2
// 1697.141 us; speedup vs baseline: 1.3112x; 1.3112x over previous
//
#include <hip/hip_runtime.h>
#include <hip/hip_bf16.h>
#include <math.h>

// BernNet: h = relu(x@W1+b1)@W2+b2 ; out = sum_m c_m A^m h (Horner) ; log_softmax
// A = D^-1/2 Adj D^-1/2 (deg from src, scatter by dst). CSR(dst) built per launch.
// SpMV gathers a prescaled bf16 vector g = dinv .* w, so per-edge = 1 gather+add.

#define NFEAT 512
#define HIDDEN 128
#define NCLASS 64
#define KORD 10

typedef unsigned short ushort_t;
typedef __attribute__((ext_vector_type(8))) short short8;
typedef __attribute__((ext_vector_type(4))) float f32x4;

static __device__ __forceinline__ float bf2f(ushort_t u) {
    return __uint_as_float(((unsigned)u) << 16);
}
static __device__ __forceinline__ ushort_t f2bf(float f) {
    __hip_bfloat16 h = __float2bfloat16(f);
    return *reinterpret_cast<ushort_t*>(&h);
}
static __device__ __forceinline__ short8 pack8(float4 a, float4 b) {
    short8 r;
    r[0] = (short)f2bf(a.x); r[1] = (short)f2bf(a.y);
    r[2] = (short)f2bf(a.z); r[3] = (short)f2bf(a.w);
    r[4] = (short)f2bf(b.x); r[5] = (short)f2bf(b.y);
    r[6] = (short)f2bf(b.z); r[7] = (short)f2bf(b.w);
    return r;
}

// ---------------- graph build ----------------

__global__ void k_degcnt(const int* __restrict__ src, const int* __restrict__ dst,
                         int* __restrict__ degi, int* __restrict__ cnti, int E) {
    int e = blockIdx.x * blockDim.x + threadIdx.x;
    if (e < E) {
        atomicAdd(&degi[src[e]], 1);
        atomicAdd(&cnti[dst[e]], 1);
    }
}

__global__ void k_dinv(const int* __restrict__ degi, float* __restrict__ dinv, int N) {
    int i = blockIdx.x * blockDim.x + threadIdx.x;
    if (i < N) {
        int d = degi[i];
        dinv[i] = (d > 0) ? rsqrtf((float)d) : 0.0f;
    }
}

// block sums: 1024 elems / block
__global__ __launch_bounds__(256) void k_blksum(const int* __restrict__ cnt,
                                                int* __restrict__ part, int n) {
    int t = threadIdx.x;
    int i0 = blockIdx.x * 1024 + t * 4;
    int s = 0;
    #pragma unroll
    for (int j = 0; j < 4; ++j) {
        int i = i0 + j;
        if (i < n) s += cnt[i];
    }
    #pragma unroll
    for (int off = 1; off < 64; off <<= 1) s += __shfl_xor(s, off);
    __shared__ int ws[4];
    if ((t & 63) == 0) ws[t >> 6] = s;
    __syncthreads();
    if (t == 0) part[blockIdx.x] = ws[0] + ws[1] + ws[2] + ws[3];
}

// exclusive scan of np (<=128) partials in place; writes row_ptr[n]=total
__global__ __launch_bounds__(128) void k_partscan(int* __restrict__ part,
                                                  int* __restrict__ row_ptr,
                                                  int np, int n, int total) {
    int t = threadIdx.x;
    int v = (t < np) ? part[t] : 0;
    int s = v;
    #pragma unroll
    for (int off = 1; off < 64; off <<= 1) {
        int u = __shfl_up(s, off);
        if ((t & 63) >= off) s += u;
    }
    __shared__ int w0;
    if (t == 63) w0 = s;
    __syncthreads();
    if (t >= 64) s += w0;
    if (t < np) part[t] = s - v;  // exclusive
    if (t == 0) row_ptr[n] = total;
}

__global__ __launch_bounds__(256) void k_blkscan(const int* __restrict__ cnt,
                                                 const int* __restrict__ part,
                                                 int* __restrict__ row_ptr,
                                                 int* __restrict__ pos, int n) {
    int t = threadIdx.x;
    int i0 = blockIdx.x * 1024 + t * 4;
    int v[4];
    int s = 0;
    #pragma unroll
    for (int j = 0; j < 4; ++j) {
        int i = i0 + j;
        v[j] = (i < n) ? cnt[i] : 0;
        s += v[j];
    }
    int ts = s;
    #pragma unroll
    for (int off = 1; off < 64; off <<= 1) {
        int u = __shfl_up(s, off);
        if ((t & 63) >= off) s += u;
    }
    int excl = s - ts;
    __shared__ int ws[4];
    if ((t & 63) == 63) ws[t >> 6] = s;
    __syncthreads();
    int wv = t >> 6, woff = 0;
    #pragma unroll
    for (int j = 0; j < 4; ++j)
        if (j < wv) woff += ws[j];
    int base = part[blockIdx.x] + woff + excl;
    #pragma unroll
    for (int j = 0; j < 4; ++j) {
        int i = i0 + j;
        if (i < n) {
            row_ptr[i] = base;
            pos[i] = base;
            base += v[j];
        }
    }
}

__global__ void k_fill(const int* __restrict__ src, const int* __restrict__ dst,
                       int* __restrict__ pos, int* __restrict__ csr, int E) {
    int e = blockIdx.x * blockDim.x + threadIdx.x;
    if (e < E) {
        int idx = atomicAdd(&pos[dst[e]], 1);
        csr[idx] = src[e];
    }
}

// ---------------- Bernstein coefficients ----------------

__global__ void k_coef(const float* __restrict__ temp, float* __restrict__ c,
                       float* __restrict__ temp_out) {
    if (threadIdx.x != 0 || blockIdx.x != 0) return;
    float T[KORD + 1];
    #pragma unroll
    for (int j = 0; j <= KORD; ++j) {
        T[j] = fmaxf(temp[j], 0.0f);
        temp_out[j] = T[j];
    }
    float binom[KORD + 1][KORD + 1];
    for (int n = 0; n <= KORD; ++n) {
        binom[n][0] = 1.0f;
        for (int k = 1; k <= n; ++k)
            binom[n][k] = (k == n) ? 1.0f : binom[n - 1][k - 1] + binom[n - 1][k];
        for (int k = n + 1; k <= KORD; ++k) binom[n][k] = 0.0f;
    }
    for (int m = 0; m <= KORD; ++m) {
        float s = 0.0f;
        for (int j = 0; j <= KORD; ++j) {
            float cj = 0.0f;
            for (int p = 0; p <= j && p <= m; ++p) {
                int q = m - p;
                if (q > KORD - j) continue;
                float t = binom[j][p] * binom[KORD - j][q];
                cj += (p & 1) ? -t : t;
            }
            s += binom[KORD][j] * T[j] * cj;
        }
        c[m] = s * (1.0f / 1024.0f);
    }
}

// ---------------- weight prep: transpose + bf16 ----------------
// W1t [128][512], W2t [64][128]

__global__ void k_prepw(const float* __restrict__ W1, const float* __restrict__ W2,
                        ushort_t* __restrict__ W1t, ushort_t* __restrict__ W2t) {
    int id = blockIdx.x * blockDim.x + threadIdx.x;
    if (id < HIDDEN * NFEAT) {
        int n = id / NFEAT, k = id % NFEAT;
        W1t[id] = f2bf(W1[(size_t)k * HIDDEN + n]);
    } else if (id < HIDDEN * NFEAT + NCLASS * HIDDEN) {
        int j = id - HIDDEN * NFEAT;
        int n = j / HIDDEN, k = j % HIDDEN;
        W2t[j] = f2bf(W2[(size_t)k * NCLASS + n]);
    }
}

// ---------------- GEMM1: h1 = relu(x @ W1 + b1), bf16 MFMA ----------------
// BM=64 BN=128 BK=64, 4 waves (2x2), wave tile 32x64 (2x4 frags of 16x16x32)

__global__ __launch_bounds__(256) void gemm1(const float* __restrict__ x,
                                             const ushort_t* __restrict__ W1t,
                                             const float* __restrict__ b1,
                                             ushort_t* __restrict__ h1, int M) {
    __shared__ char smem[24576];
    char* As = smem;          // [64 m][64 k] bf16, row stride 128B, XOR swizzle
    char* Bs = smem + 8192;   // [128 n][64 k] bf16, row stride 128B, XOR swizzle
    const int t = threadIdx.x;
    const int m0 = blockIdx.x * 64;
    const int wid = t >> 6, lane = t & 63;
    const int wr = wid >> 1, wc = wid & 1;
    const int lm = lane & 15, lg = lane >> 4;

    f32x4 acc[2][4];
    #pragma unroll
    for (int i = 0; i < 2; ++i)
        #pragma unroll
        for (int j = 0; j < 4; ++j) acc[i][j] = (f32x4){0.f, 0.f, 0.f, 0.f};

    for (int k0 = 0; k0 < NFEAT; k0 += 64) {
        #pragma unroll
        for (int i = 0; i < 2; ++i) {  // A: 512 chunks of 8 floats -> 8 bf16
            int idx = t + i * 256;
            int r = idx >> 3, c8 = idx & 7;
            float4 v0 = make_float4(0.f, 0.f, 0.f, 0.f), v1 = v0;
            if (m0 + r < M) {
                const float* p = &x[(size_t)(m0 + r) * NFEAT + k0 + c8 * 8];
                v0 = *(const float4*)p;
                v1 = *(const float4*)(p + 4);
            }
            *(short8*)(As + r * 128 + ((c8 * 16) ^ ((r & 7) << 4))) = pack8(v0, v1);
        }
        #pragma unroll
        for (int i = 0; i < 4; ++i) {  // B: 1024 chunks of 8 bf16
            int idx = t + i * 256;
            int r = idx >> 3, c8 = idx & 7;
            short8 v = *(const short8*)&W1t[(size_t)r * NFEAT + k0 + c8 * 8];
            *(short8*)(Bs + r * 128 + ((c8 * 16) ^ ((r & 7) << 4))) = v;
        }
        __syncthreads();
        #pragma unroll
        for (int kk = 0; kk < 64; kk += 32) {
            int kb = (kk + lg * 8) * 2;
            short8 af[2], bfr[4];
            #pragma unroll
            for (int fi = 0; fi < 2; ++fi) {
                int m = wr * 32 + fi * 16 + lm;
                af[fi] = *(const short8*)(As + m * 128 + (kb ^ ((m & 7) << 4)));
            }
            #pragma unroll
            for (int fj = 0; fj < 4; ++fj) {
                int n = wc * 64 + fj * 16 + lm;
                bfr[fj] = *(const short8*)(Bs + n * 128 + (kb ^ ((n & 7) << 4)));
            }
            #pragma unroll
            for (int fi = 0; fi < 2; ++fi)
                #pragma unroll
                for (int fj = 0; fj < 4; ++fj)
                    acc[fi][fj] = __builtin_amdgcn_mfma_f32_16x16x32_bf16(
                        af[fi], bfr[fj], acc[fi][fj], 0, 0, 0);
        }
        __syncthreads();
    }

    // epilogue: bias+relu -> bf16, repack via LDS for coalesced stores
    ushort_t* Cs = (ushort_t*)smem;  // [64][128]
    #pragma unroll
    for (int fi = 0; fi < 2; ++fi)
        #pragma unroll
        for (int fj = 0; fj < 4; ++fj) {
            int col = wc * 64 + fj * 16 + lm;
            float bb = b1[col];
            #pragma unroll
            for (int q = 0; q < 4; ++q) {
                int r = wr * 32 + fi * 16 + lg * 4 + q;
                float z = fmaxf(acc[fi][fj][q] + bb, 0.0f);
                Cs[r * 128 + col] = f2bf(z);
            }
        }
    __syncthreads();
    #pragma unroll
    for (int i = 0; i < 4; ++i) {  // 1024 chunks of 8 ushort
        int idx = t + i * 256;
        int r = idx >> 4, c8 = idx & 15;
        if (m0 + r < M)
            *(short8*)&h1[(size_t)(m0 + r) * HIDDEN + c8 * 8] =
                *(const short8*)&Cs[r * 128 + c8 * 8];
    }
}

// ---------------- GEMM2: h = h1 @ W2 + b2 ; emits hb=bf16(h), g0=bf16(dinv*cK*h) ----
// BM=128 BN=64 K=128 (single stage), 4 waves (4x1), wave tile 32x64

__global__ __launch_bounds__(256) void gemm2(const ushort_t* __restrict__ h1,
                                             const ushort_t* __restrict__ W2t,
                                             const float* __restrict__ b2,
                                             const float* __restrict__ dinv,
                                             const float* __restrict__ c,
                                             ushort_t* __restrict__ hb,
                                             ushort_t* __restrict__ g0, int M) {
    __shared__ char smem[49152];
    char* As = smem;           // [128 m][128 k] bf16, row stride 256B
    char* Bs = smem + 32768;   // [64 n][128 k] bf16, row stride 256B
    const int t = threadIdx.x;
    const int m0 = blockIdx.x * 128;
    const int wr = t >> 6, lane = t & 63;
    const int lm = lane & 15, lg = lane >> 4;

    #pragma unroll
    for (int i = 0; i < 8; ++i) {  // A: 2048 chunks of 8 bf16
        int idx = t + i * 256;
        int r = idx >> 4, c8 = idx & 15;
        short8 v = (short8){0, 0, 0, 0, 0, 0, 0, 0};
        if (m0 + r < M) v = *(const short8*)&h1[(size_t)(m0 + r) * HIDDEN + c8 * 8];
        *(short8*)(As + r * 256 + ((c8 * 16) ^ ((r & 7) << 4))) = v;
    }
    #pragma unroll
    for (int i = 0; i < 4; ++i) {  // B: 1024 chunks of 8 bf16
        int idx = t + i * 256;
        int r = idx >> 4, c8 = idx & 15;
        short8 v = *(const short8*)&W2t[(size_t)r * HIDDEN + c8 * 8];
        *(short8*)(Bs + r * 256 + ((c8 * 16) ^ ((r & 7) << 4))) = v;
    }
    __syncthreads();

    f32x4 acc[2][4];
    #pragma unroll
    for (int i = 0; i < 2; ++i)
        #pragma unroll
        for (int j = 0; j < 4; ++j) acc[i][j] = (f32x4){0.f, 0.f, 0.f, 0.f};

    #pragma unroll
    for (int kk = 0; kk < HIDDEN; kk += 32) {
        int kb = (kk + lg * 8) * 2;
        short8 af[2], bfr[4];
        #pragma unroll
        for (int fi = 0; fi < 2; ++fi) {
            int m = wr * 32 + fi * 16 + lm;
            af[fi] = *(const short8*)(As + m * 256 + (kb ^ ((m & 7) << 4)));
        }
        #pragma unroll
        for (int fj = 0; fj < 4; ++fj) {
            int n = fj * 16 + lm;
            bfr[fj] = *(const short8*)(Bs + n * 256 + (kb ^ ((n & 7) << 4)));
        }
        #pragma unroll
        for (int fi = 0; fi < 2; ++fi)
            #pragma unroll
            for (int fj = 0; fj < 4; ++fj)
                acc[fi][fj] = __builtin_amdgcn_mfma_f32_16x16x32_bf16(
                    af[fi], bfr[fj], acc[fi][fj], 0, 0, 0);
    }

    float cK = c[KORD];
    #pragma unroll
    for (int fi = 0; fi < 2; ++fi)
        #pragma unroll
        for (int q = 0; q < 4; ++q) {
            int r = m0 + wr * 32 + fi * 16 + lg * 4 + q;
            if (r < M) {
                float dv = dinv[r];
                #pragma unroll
                for (int fj = 0; fj < 4; ++fj) {
                    int col = fj * 16 + lm;
                    float z = acc[fi][fj][q] + b2[col];
                    size_t o = (size_t)r * NCLASS + col;
                    hb[o] = f2bf(z);
                    g0[o] = f2bf(dv * cK * z);
                }
            }
        }
}

// ---------------- Horner SpMV step: w = A*w_prev + c[cidx]*h ----------------
// gin = bf16(dinv .* w_prev); per edge: acc += gin[src]; row scale dinv[dst].
// last step fuses log_softmax and writes fp32 out.

__global__ __launch_bounds__(256) void k_adj(const ushort_t* __restrict__ gin,
                                             const ushort_t* __restrict__ hb,
                                             const float* __restrict__ dinv,
                                             const int* __restrict__ row_ptr,
                                             const int* __restrict__ csr,
                                             const float* __restrict__ c, int cidx,
                                             ushort_t* __restrict__ gout,
                                             float* __restrict__ out, int last, int N) {
    int wid = blockIdx.x * 4 + (threadIdx.x >> 6);
    int lane = threadIdx.x & 63;
    if (wid >= N) return;
    int b = row_ptr[wid], e = row_ptr[wid + 1];
    float a0 = 0.f, a1 = 0.f, a2 = 0.f, a3 = 0.f;
    int i = b;
    for (; i + 3 < e; i += 4) {
        int s0 = csr[i], s1 = csr[i + 1], s2 = csr[i + 2], s3 = csr[i + 3];
        a0 += bf2f(gin[(size_t)s0 * NCLASS + lane]);
        a1 += bf2f(gin[(size_t)s1 * NCLASS + lane]);
        a2 += bf2f(gin[(size_t)s2 * NCLASS + lane]);
        a3 += bf2f(gin[(size_t)s3 * NCLASS + lane]);
    }
    for (; i < e; ++i) a0 += bf2f(gin[(size_t)csr[i] * NCLASS + lane]);
    float dv = dinv[wid];
    size_t o = (size_t)wid * NCLASS + lane;
    float w = dv * ((a0 + a1) + (a2 + a3)) + c[cidx] * bf2f(hb[o]);
    if (!last) {
        gout[o] = f2bf(dv * w);
    } else {
        float mx = w;
        #pragma unroll
        for (int off = 32; off >= 1; off >>= 1) mx = fmaxf(mx, __shfl_xor(mx, off));
        float ex = expf(w - mx), s = ex;
        #pragma unroll
        for (int off = 32; off >= 1; off >>= 1) s += __shfl_xor(s, off);
        out[o] = w - mx - logf(s);
    }
}

// ---------------- launch ----------------

extern "C" void kernel_launch(void* const* d_in, const int* in_sizes, int n_in,
                              void* d_out, int out_size, void* d_ws, size_t ws_size,
                              hipStream_t stream) {
    const float* x = (const float*)d_in[0];
    const int* ei = (const int*)d_in[1];
    const float* W1 = (const float*)d_in[2];
    const float* b1 = (const float*)d_in[3];
    const float* W2 = (const float*)d_in[4];
    const float* b2 = (const float*)d_in[5];
    const float* temp = (const float*)d_in[6];

    const int N = in_sizes[0] / NFEAT;  // 100000
    const int E = in_sizes[1] / 2;      // 3200000
    const int* src = ei;
    const int* dst = ei + E;

    float* out = (float*)d_out;
    float* temp_out = out + (size_t)N * NCLASS;

    char* ws = (char*)d_ws;
    size_t off = 0;
    auto alloc = [&](size_t bytes) {
        char* p = ws + off;
        off = (off + bytes + 255) & ~(size_t)255;
        return p;
    };
    ushort_t* h1 = (ushort_t*)alloc((size_t)N * HIDDEN * sizeof(ushort_t));
    ushort_t* hb = (ushort_t*)alloc((size_t)N * NCLASS * sizeof(ushort_t));
    ushort_t* gA = (ushort_t*)alloc((size_t)N * NCLASS * sizeof(ushort_t));
    ushort_t* gB = (ushort_t*)alloc((size_t)N * NCLASS * sizeof(ushort_t));
    int* degi = (int*)alloc((size_t)N * sizeof(int));
    float* dinv = (float*)alloc((size_t)N * sizeof(float));
    int* cnti = (int*)alloc((size_t)N * sizeof(int));
    int* row_ptr = (int*)alloc((size_t)(N + 1) * sizeof(int));
    int* pos = (int*)alloc((size_t)N * sizeof(int));
    int* part = (int*)alloc(256 * sizeof(int));
    int* csr = (int*)alloc((size_t)E * sizeof(int));
    ushort_t* W1t = (ushort_t*)alloc((size_t)HIDDEN * NFEAT * sizeof(ushort_t));
    ushort_t* W2t = (ushort_t*)alloc((size_t)NCLASS * HIDDEN * sizeof(ushort_t));
    float* c = (float*)alloc(64);
    (void)ws_size;

    const int TB = 256;
    const int egrid = (E + TB - 1) / TB;
    const int ngrid = (N + TB - 1) / TB;
    const int nb = (N + 1023) / 1024;  // 98 <= 128
    const int wgrid = (N + 3) / 4;

    hipMemsetAsync(degi, 0, (size_t)N * sizeof(int), stream);
    hipMemsetAsync(cnti, 0, (size_t)N * sizeof(int), stream);
    k_degcnt<<<egrid, TB, 0, stream>>>(src, dst, degi, cnti, E);
    k_dinv<<<ngrid, TB, 0, stream>>>(degi, dinv, N);
    k_blksum<<<nb, TB, 0, stream>>>(cnti, part, N);
    k_partscan<<<1, 128, 0, stream>>>(part, row_ptr, nb, N, E);
    k_blkscan<<<nb, TB, 0, stream>>>(cnti, part, row_ptr, pos, N);
    k_fill<<<egrid, TB, 0, stream>>>(src, dst, pos, csr, E);

    k_coef<<<1, 64, 0, stream>>>(temp, c, temp_out);
    k_prepw<<<(HIDDEN * NFEAT + NCLASS * HIDDEN + TB - 1) / TB, TB, 0, stream>>>(W1, W2, W1t, W2t);

    gemm1<<<(N + 63) / 64, TB, 0, stream>>>(x, W1t, b1, h1, N);
    gemm2<<<(N + 127) / 128, TB, 0, stream>>>(h1, W2t, b2, dinv, c, hb, gA, N);

    const ushort_t* gin = gA;
    ushort_t* gout = gB;
    for (int s = 1; s <= KORD; ++s) {
        int last = (s == KORD) ? 1 : 0;
        k_adj<<<wgrid, TB, 0, stream>>>(gin, hb, dinv, row_ptr, csr, c, KORD - s,
                                        gout, out, last, N);
        const ushort_t* tmp = gin;
        gin = gout;
        gout = (ushort_t*)tmp;
    }
}

// Round 3
// 1384.127 us; speedup vs baseline: 1.6078x; 1.2261x over previous
//
#include <hip/hip_runtime.h>
#include <hip/hip_bf16.h>
#include <math.h>

// BernNet: h = relu(x@W1+b1)@W2+b2 ; out = sum_m c_m A^m h (Horner) ; log_softmax
// A = D^-1/2 Adj D^-1/2 (deg from src, scatter by dst). CSR(dst) built per launch
// via bucketed two-phase counting sort (64 dst-nodes per bucket).

#define NFEAT 512
#define HIDDEN 128
#define NCLASS 64
#define KORD 10
#define CH 8192        // edges per block in bucket passes
#define MAXBUCK 1600   // LDS histogram capacity (N <= 102400)

typedef unsigned short ushort_t;
typedef __attribute__((ext_vector_type(8))) short short8;
typedef __attribute__((ext_vector_type(4))) float f32x4;

static __device__ __forceinline__ float bf2f(ushort_t u) {
    return __uint_as_float(((unsigned)u) << 16);
}
static __device__ __forceinline__ ushort_t f2bf(float f) {
    __hip_bfloat16 h = __float2bfloat16(f);
    return *reinterpret_cast<ushort_t*>(&h);
}
static __device__ __forceinline__ short8 pack8(float4 a, float4 b) {
    short8 r;
    r[0] = (short)f2bf(a.x); r[1] = (short)f2bf(a.y);
    r[2] = (short)f2bf(a.z); r[3] = (short)f2bf(a.w);
    r[4] = (short)f2bf(b.x); r[5] = (short)f2bf(b.y);
    r[6] = (short)f2bf(b.z); r[7] = (short)f2bf(b.w);
    return r;
}

// ---------------- graph build: bucketed counting sort ----------------

// phase 0: bucket histogram (bucket = dst >> 6), LDS-aggregated
__global__ __launch_bounds__(256) void p0_hist(const int* __restrict__ dst,
                                               int* __restrict__ bhist, int E, int nbuck) {
    __shared__ int h[MAXBUCK];
    for (int i = threadIdx.x; i < nbuck; i += 256) h[i] = 0;
    __syncthreads();
    int base = blockIdx.x * CH;
    for (int j = threadIdx.x; j < CH; j += 256) {
        int e = base + j;
        if (e < E) atomicAdd(&h[dst[e] >> 6], 1);
    }
    __syncthreads();
    for (int i = threadIdx.x; i < nbuck; i += 256) {
        int v = h[i];
        if (v) atomicAdd(&bhist[i], v);
    }
}

// exclusive scan of bhist -> bstart (and gpos copy); sets sentinels
__global__ __launch_bounds__(256) void p_scan(const int* __restrict__ bhist,
                                              int* __restrict__ bstart,
                                              int* __restrict__ gpos, int nbuck,
                                              int* __restrict__ row_ptr, int N, int E) {
    __shared__ int ws[4];
    __shared__ int carry;
    int t = threadIdx.x, lane = t & 63, w = t >> 6;
    if (t == 0) carry = 0;
    __syncthreads();
    for (int base = 0; base < nbuck; base += 256) {
        int i = base + t;
        int v = (i < nbuck) ? bhist[i] : 0;
        int s = v;
        #pragma unroll
        for (int off = 1; off < 64; off <<= 1) {
            int u = __shfl_up(s, off);
            if (lane >= off) s += u;
        }
        if (lane == 63) ws[w] = s;
        __syncthreads();
        int pre = 0;
        #pragma unroll
        for (int j = 0; j < 4; ++j)
            if (j < w) pre += ws[j];
        int excl = carry + pre + s - v;
        if (i < nbuck) {
            bstart[i] = excl;
            gpos[i] = excl;
        }
        __syncthreads();
        if (t == 255) carry += pre + s;
        __syncthreads();
    }
    if (t == 0) {
        bstart[nbuck] = E;
        row_ptr[N] = E;
    }
}

// phase 1: scatter packed (src | dstlow<<17) into bucket regions; fold deg[src] atomics
__global__ __launch_bounds__(256) void p1_scatter(const int* __restrict__ src,
                                                  const int* __restrict__ dst,
                                                  int* __restrict__ gpos,
                                                  int* __restrict__ buf,
                                                  int* __restrict__ degi, int E, int nbuck) {
    __shared__ int h[MAXBUCK];
    __shared__ int b[MAXBUCK];
    for (int i = threadIdx.x; i < nbuck; i += 256) h[i] = 0;
    __syncthreads();
    int base = blockIdx.x * CH;
    for (int j = threadIdx.x; j < CH; j += 256) {
        int e = base + j;
        if (e < E) atomicAdd(&h[dst[e] >> 6], 1);
    }
    __syncthreads();
    for (int i = threadIdx.x; i < nbuck; i += 256) {
        int v = h[i];
        b[i] = v ? atomicAdd(&gpos[i], v) : 0;
        h[i] = 0;
    }
    __syncthreads();
    for (int j = threadIdx.x; j < CH; j += 256) {
        int e = base + j;
        if (e < E) {
            int d = dst[e], s = src[e];
            int bk = d >> 6;
            int off = atomicAdd(&h[bk], 1);
            buf[b[bk] + off] = s | ((d & 63) << 17);
            atomicAdd(&degi[s], 1);
        }
    }
}

// phase 2: per-bucket grouping into final CSR + row_ptr (all-LDS, hot L2 region)
__global__ __launch_bounds__(256) void p2_group(const int* __restrict__ buf,
                                                const int* __restrict__ bstart,
                                                int* __restrict__ csr,
                                                int* __restrict__ row_ptr, int N) {
    int bk = blockIdx.x;
    int s0 = bstart[bk], s1 = bstart[bk + 1];
    __shared__ int cnt[64];
    __shared__ int pos[64];
    int t = threadIdx.x;
    if (t < 64) cnt[t] = 0;
    __syncthreads();
    for (int i = s0 + t; i < s1; i += 256) atomicAdd(&cnt[buf[i] >> 17], 1);
    __syncthreads();
    if (t < 64) {
        int v = cnt[t], s = v;
        #pragma unroll
        for (int off = 1; off < 64; off <<= 1) {
            int u = __shfl_up(s, off);
            if (t >= off) s += u;
        }
        int excl = s - v;
        int node = bk * 64 + t;
        if (node < N) row_ptr[node] = s0 + excl;
        pos[t] = s0 + excl;
    }
    __syncthreads();
    for (int i = s0 + t; i < s1; i += 256) {
        int p = buf[i];
        int off = atomicAdd(&pos[p >> 17], 1);
        csr[off] = p & 0x1FFFF;
    }
}

__global__ void k_dinv(const int* __restrict__ degi, float* __restrict__ dinv, int N) {
    int i = blockIdx.x * blockDim.x + threadIdx.x;
    if (i < N) {
        int d = degi[i];
        dinv[i] = (d > 0) ? rsqrtf((float)d) : 0.0f;
    }
}

// ---------------- Bernstein coefficients ----------------

__global__ void k_coef(const float* __restrict__ temp, float* __restrict__ c,
                       float* __restrict__ temp_out) {
    if (threadIdx.x != 0 || blockIdx.x != 0) return;
    float T[KORD + 1];
    #pragma unroll
    for (int j = 0; j <= KORD; ++j) {
        T[j] = fmaxf(temp[j], 0.0f);
        temp_out[j] = T[j];
    }
    float binom[KORD + 1][KORD + 1];
    for (int n = 0; n <= KORD; ++n) {
        binom[n][0] = 1.0f;
        for (int k = 1; k <= n; ++k)
            binom[n][k] = (k == n) ? 1.0f : binom[n - 1][k - 1] + binom[n - 1][k];
        for (int k = n + 1; k <= KORD; ++k) binom[n][k] = 0.0f;
    }
    for (int m = 0; m <= KORD; ++m) {
        float s = 0.0f;
        for (int j = 0; j <= KORD; ++j) {
            float cj = 0.0f;
            for (int p = 0; p <= j && p <= m; ++p) {
                int q = m - p;
                if (q > KORD - j) continue;
                float t = binom[j][p] * binom[KORD - j][q];
                cj += (p & 1) ? -t : t;
            }
            s += binom[KORD][j] * T[j] * cj;
        }
        c[m] = s * (1.0f / 1024.0f);
    }
}

// ---------------- weight prep: transpose + bf16 ----------------

__global__ void k_prepw(const float* __restrict__ W1, const float* __restrict__ W2,
                        ushort_t* __restrict__ W1t, ushort_t* __restrict__ W2t) {
    int id = blockIdx.x * blockDim.x + threadIdx.x;
    if (id < HIDDEN * NFEAT) {
        int n = id / NFEAT, k = id % NFEAT;
        W1t[id] = f2bf(W1[(size_t)k * HIDDEN + n]);
    } else if (id < HIDDEN * NFEAT + NCLASS * HIDDEN) {
        int j = id - HIDDEN * NFEAT;
        int n = j / HIDDEN, k = j % HIDDEN;
        W2t[j] = f2bf(W2[(size_t)k * NCLASS + n]);
    }
}

// ---------------- GEMM1: h1 = relu(x @ W1 + b1), bf16 MFMA ----------------

__global__ __launch_bounds__(256) void gemm1(const float* __restrict__ x,
                                             const ushort_t* __restrict__ W1t,
                                             const float* __restrict__ b1,
                                             ushort_t* __restrict__ h1, int M) {
    __shared__ char smem[24576];
    char* As = smem;
    char* Bs = smem + 8192;
    const int t = threadIdx.x;
    const int m0 = blockIdx.x * 64;
    const int wid = t >> 6, lane = t & 63;
    const int wr = wid >> 1, wc = wid & 1;
    const int lm = lane & 15, lg = lane >> 4;

    f32x4 acc[2][4];
    #pragma unroll
    for (int i = 0; i < 2; ++i)
        #pragma unroll
        for (int j = 0; j < 4; ++j) acc[i][j] = (f32x4){0.f, 0.f, 0.f, 0.f};

    for (int k0 = 0; k0 < NFEAT; k0 += 64) {
        #pragma unroll
        for (int i = 0; i < 2; ++i) {
            int idx = t + i * 256;
            int r = idx >> 3, c8 = idx & 7;
            float4 v0 = make_float4(0.f, 0.f, 0.f, 0.f), v1 = v0;
            if (m0 + r < M) {
                const float* p = &x[(size_t)(m0 + r) * NFEAT + k0 + c8 * 8];
                v0 = *(const float4*)p;
                v1 = *(const float4*)(p + 4);
            }
            *(short8*)(As + r * 128 + ((c8 * 16) ^ ((r & 7) << 4))) = pack8(v0, v1);
        }
        #pragma unroll
        for (int i = 0; i < 4; ++i) {
            int idx = t + i * 256;
            int r = idx >> 3, c8 = idx & 7;
            short8 v = *(const short8*)&W1t[(size_t)r * NFEAT + k0 + c8 * 8];
            *(short8*)(Bs + r * 128 + ((c8 * 16) ^ ((r & 7) << 4))) = v;
        }
        __syncthreads();
        #pragma unroll
        for (int kk = 0; kk < 64; kk += 32) {
            int kb = (kk + lg * 8) * 2;
            short8 af[2], bfr[4];
            #pragma unroll
            for (int fi = 0; fi < 2; ++fi) {
                int m = wr * 32 + fi * 16 + lm;
                af[fi] = *(const short8*)(As + m * 128 + (kb ^ ((m & 7) << 4)));
            }
            #pragma unroll
            for (int fj = 0; fj < 4; ++fj) {
                int n = wc * 64 + fj * 16 + lm;
                bfr[fj] = *(const short8*)(Bs + n * 128 + (kb ^ ((n & 7) << 4)));
            }
            #pragma unroll
            for (int fi = 0; fi < 2; ++fi)
                #pragma unroll
                for (int fj = 0; fj < 4; ++fj)
                    acc[fi][fj] = __builtin_amdgcn_mfma_f32_16x16x32_bf16(
                        af[fi], bfr[fj], acc[fi][fj], 0, 0, 0);
        }
        __syncthreads();
    }

    ushort_t* Cs = (ushort_t*)smem;
    #pragma unroll
    for (int fi = 0; fi < 2; ++fi)
        #pragma unroll
        for (int fj = 0; fj < 4; ++fj) {
            int col = wc * 64 + fj * 16 + lm;
            float bb = b1[col];
            #pragma unroll
            for (int q = 0; q < 4; ++q) {
                int r = wr * 32 + fi * 16 + lg * 4 + q;
                float z = fmaxf(acc[fi][fj][q] + bb, 0.0f);
                Cs[r * 128 + col] = f2bf(z);
            }
        }
    __syncthreads();
    #pragma unroll
    for (int i = 0; i < 4; ++i) {
        int idx = t + i * 256;
        int r = idx >> 4, c8 = idx & 15;
        if (m0 + r < M)
            *(short8*)&h1[(size_t)(m0 + r) * HIDDEN + c8 * 8] =
                *(const short8*)&Cs[r * 128 + c8 * 8];
    }
}

// ---------------- GEMM2: h = h1 @ W2 + b2 ; emits hb, g0 = bf16(dinv*cK*h) ----

__global__ __launch_bounds__(256) void gemm2(const ushort_t* __restrict__ h1,
                                             const ushort_t* __restrict__ W2t,
                                             const float* __restrict__ b2,
                                             const float* __restrict__ dinv,
                                             const float* __restrict__ c,
                                             ushort_t* __restrict__ hb,
                                             ushort_t* __restrict__ g0, int M) {
    __shared__ char smem[49152];
    char* As = smem;
    char* Bs = smem + 32768;
    const int t = threadIdx.x;
    const int m0 = blockIdx.x * 128;
    const int wr = t >> 6, lane = t & 63;
    const int lm = lane & 15, lg = lane >> 4;

    #pragma unroll
    for (int i = 0; i < 8; ++i) {
        int idx = t + i * 256;
        int r = idx >> 4, c8 = idx & 15;
        short8 v = (short8){0, 0, 0, 0, 0, 0, 0, 0};
        if (m0 + r < M) v = *(const short8*)&h1[(size_t)(m0 + r) * HIDDEN + c8 * 8];
        *(short8*)(As + r * 256 + ((c8 * 16) ^ ((r & 7) << 4))) = v;
    }
    #pragma unroll
    for (int i = 0; i < 4; ++i) {
        int idx = t + i * 256;
        int r = idx >> 4, c8 = idx & 15;
        short8 v = *(const short8*)&W2t[(size_t)r * HIDDEN + c8 * 8];
        *(short8*)(Bs + r * 256 + ((c8 * 16) ^ ((r & 7) << 4))) = v;
    }
    __syncthreads();

    f32x4 acc[2][4];
    #pragma unroll
    for (int i = 0; i < 2; ++i)
        #pragma unroll
        for (int j = 0; j < 4; ++j) acc[i][j] = (f32x4){0.f, 0.f, 0.f, 0.f};

    #pragma unroll
    for (int kk = 0; kk < HIDDEN; kk += 32) {
        int kb = (kk + lg * 8) * 2;
        short8 af[2], bfr[4];
        #pragma unroll
        for (int fi = 0; fi < 2; ++fi) {
            int m = wr * 32 + fi * 16 + lm;
            af[fi] = *(const short8*)(As + m * 256 + (kb ^ ((m & 7) << 4)));
        }
        #pragma unroll
        for (int fj = 0; fj < 4; ++fj) {
            int n = fj * 16 + lm;
            bfr[fj] = *(const short8*)(Bs + n * 256 + (kb ^ ((n & 7) << 4)));
        }
        #pragma unroll
        for (int fi = 0; fi < 2; ++fi)
            #pragma unroll
            for (int fj = 0; fj < 4; ++fj)
                acc[fi][fj] = __builtin_amdgcn_mfma_f32_16x16x32_bf16(
                    af[fi], bfr[fj], acc[fi][fj], 0, 0, 0);
    }

    float cK = c[KORD];
    #pragma unroll
    for (int fi = 0; fi < 2; ++fi)
        #pragma unroll
        for (int q = 0; q < 4; ++q) {
            int r = m0 + wr * 32 + fi * 16 + lg * 4 + q;
            if (r < M) {
                float dv = dinv[r];
                #pragma unroll
                for (int fj = 0; fj < 4; ++fj) {
                    int col = fj * 16 + lm;
                    float z = acc[fi][fj][q] + b2[col];
                    size_t o = (size_t)r * NCLASS + col;
                    hb[o] = f2bf(z);
                    g0[o] = f2bf(dv * cK * z);
                }
            }
        }
}

// ---------------- Horner SpMV step: w = A*w_prev + c[cidx]*h ----------------

__global__ __launch_bounds__(256) void k_adj(const ushort_t* __restrict__ gin,
                                             const ushort_t* __restrict__ hb,
                                             const float* __restrict__ dinv,
                                             const int* __restrict__ row_ptr,
                                             const int* __restrict__ csr,
                                             const float* __restrict__ c, int cidx,
                                             ushort_t* __restrict__ gout,
                                             float* __restrict__ out, int last, int N) {
    int wid = blockIdx.x * 4 + (threadIdx.x >> 6);
    int lane = threadIdx.x & 63;
    if (wid >= N) return;
    int b = row_ptr[wid], e = row_ptr[wid + 1];
    float a0 = 0.f, a1 = 0.f, a2 = 0.f, a3 = 0.f;
    int i = b;
    for (; i + 3 < e; i += 4) {
        int s0 = csr[i], s1 = csr[i + 1], s2 = csr[i + 2], s3 = csr[i + 3];
        a0 += bf2f(gin[(size_t)s0 * NCLASS + lane]);
        a1 += bf2f(gin[(size_t)s1 * NCLASS + lane]);
        a2 += bf2f(gin[(size_t)s2 * NCLASS + lane]);
        a3 += bf2f(gin[(size_t)s3 * NCLASS + lane]);
    }
    for (; i < e; ++i) a0 += bf2f(gin[(size_t)csr[i] * NCLASS + lane]);
    float dv = dinv[wid];
    size_t o = (size_t)wid * NCLASS + lane;
    float w = dv * ((a0 + a1) + (a2 + a3)) + c[cidx] * bf2f(hb[o]);
    if (!last) {
        gout[o] = f2bf(dv * w);
    } else {
        float mx = w;
        #pragma unroll
        for (int off = 32; off >= 1; off >>= 1) mx = fmaxf(mx, __shfl_xor(mx, off));
        float ex = expf(w - mx), s = ex;
        #pragma unroll
        for (int off = 32; off >= 1; off >>= 1) s += __shfl_xor(s, off);
        out[o] = w - mx - logf(s);
    }
}

// ---------------- launch ----------------

extern "C" void kernel_launch(void* const* d_in, const int* in_sizes, int n_in,
                              void* d_out, int out_size, void* d_ws, size_t ws_size,
                              hipStream_t stream) {
    const float* x = (const float*)d_in[0];
    const int* ei = (const int*)d_in[1];
    const float* W1 = (const float*)d_in[2];
    const float* b1 = (const float*)d_in[3];
    const float* W2 = (const float*)d_in[4];
    const float* b2 = (const float*)d_in[5];
    const float* temp = (const float*)d_in[6];

    const int N = in_sizes[0] / NFEAT;  // 100000
    const int E = in_sizes[1] / 2;      // 3200000
    const int* src = ei;
    const int* dst = ei + E;
    const int nbuck = (N + 63) >> 6;    // 1563

    float* out = (float*)d_out;
    float* temp_out = out + (size_t)N * NCLASS;

    char* ws = (char*)d_ws;
    size_t off = 0;
    auto alloc = [&](size_t bytes) {
        char* p = ws + off;
        off = (off + bytes + 255) & ~(size_t)255;
        return p;
    };
    ushort_t* h1 = (ushort_t*)alloc((size_t)N * HIDDEN * sizeof(ushort_t));
    ushort_t* hb = (ushort_t*)alloc((size_t)N * NCLASS * sizeof(ushort_t));
    ushort_t* gA = (ushort_t*)alloc((size_t)N * NCLASS * sizeof(ushort_t));
    ushort_t* gB = (ushort_t*)alloc((size_t)N * NCLASS * sizeof(ushort_t));
    int* degi = (int*)alloc((size_t)N * sizeof(int));
    float* dinv = (float*)alloc((size_t)N * sizeof(float));
    int* row_ptr = (int*)alloc((size_t)(N + 1) * sizeof(int));
    int* bhist = (int*)alloc((size_t)MAXBUCK * sizeof(int));
    int* bstart = (int*)alloc((size_t)(MAXBUCK + 1) * sizeof(int));
    int* gpos = (int*)alloc((size_t)MAXBUCK * sizeof(int));
    int* csr = (int*)alloc((size_t)E * sizeof(int));
    ushort_t* W1t = (ushort_t*)alloc((size_t)HIDDEN * NFEAT * sizeof(ushort_t));
    ushort_t* W2t = (ushort_t*)alloc((size_t)NCLASS * HIDDEN * sizeof(ushort_t));
    float* c = (float*)alloc(64);
    (void)ws_size;

    int* buf = (int*)h1;  // bucket-scattered edges; dead before gemm1 writes h1

    const int TB = 256;
    const int ngrid = (N + TB - 1) / TB;
    const int eg = (E + CH - 1) / CH;  // 391
    const int wgrid = (N + 3) / 4;

    hipMemsetAsync(degi, 0, (size_t)N * sizeof(int), stream);
    hipMemsetAsync(bhist, 0, (size_t)nbuck * sizeof(int), stream);
    p0_hist<<<eg, TB, 0, stream>>>(dst, bhist, E, nbuck);
    p_scan<<<1, TB, 0, stream>>>(bhist, bstart, gpos, nbuck, row_ptr, N, E);
    p1_scatter<<<eg, TB, 0, stream>>>(src, dst, gpos, buf, degi, E, nbuck);
    k_dinv<<<ngrid, TB, 0, stream>>>(degi, dinv, N);
    p2_group<<<nbuck, TB, 0, stream>>>(buf, bstart, csr, row_ptr, N);

    k_coef<<<1, 64, 0, stream>>>(temp, c, temp_out);
    k_prepw<<<(HIDDEN * NFEAT + NCLASS * HIDDEN + TB - 1) / TB, TB, 0, stream>>>(W1, W2, W1t, W2t);

    gemm1<<<(N + 63) / 64, TB, 0, stream>>>(x, W1t, b1, h1, N);
    gemm2<<<(N + 127) / 128, TB, 0, stream>>>(h1, W2t, b2, dinv, c, hb, gA, N);

    const ushort_t* gin = gA;
    ushort_t* gout = gB;
    for (int s = 1; s <= KORD; ++s) {
        int last = (s == KORD) ? 1 : 0;
        k_adj<<<wgrid, TB, 0, stream>>>(gin, hb, dinv, row_ptr, csr, c, KORD - s,
                                        gout, out, last, N);
        const ushort_t* tmp = gin;
        gin = gout;
        gout = (ushort_t*)tmp;
    }
}

// Round 4
// 1148.159 us; speedup vs baseline: 1.9382x; 1.2055x over previous
//
#include <hip/hip_runtime.h>
#include <hip/hip_bf16.h>
#include <math.h>

// BernNet: h = relu(x@W1+b1)@W2+b2 ; out = sum_m c_m A^m h (Horner) ; log_softmax
// A = D^-1/2 Adj D^-1/2 (deg from src, scatter by dst). CSR(dst) built per launch
// via bucketed two-phase counting sort (64 dst-nodes per bucket, 128 scatter blocks
// so each (block,bucket) run ~= one 64B line -> full-line writebacks).

#define NFEAT 512
#define HIDDEN 128
#define NCLASS 64
#define KORD 10
#define MAXBUCK 1600   // LDS histogram capacity (N <= 102400)
#define NSCAT 128      // scatter blocks: run length E/NSCAT/nbuck ~= 16 ints = 1 line

typedef unsigned short ushort_t;
typedef __attribute__((ext_vector_type(8))) short short8;
typedef __attribute__((ext_vector_type(4))) float f32x4;
typedef __attribute__((ext_vector_type(4))) unsigned short us4v;

static __device__ __forceinline__ float bf2f(ushort_t u) {
    return __uint_as_float(((unsigned)u) << 16);
}
static __device__ __forceinline__ ushort_t f2bf(float f) {
    __hip_bfloat16 h = __float2bfloat16(f);
    return *reinterpret_cast<ushort_t*>(&h);
}
static __device__ __forceinline__ short8 pack8(float4 a, float4 b) {
    short8 r;
    r[0] = (short)f2bf(a.x); r[1] = (short)f2bf(a.y);
    r[2] = (short)f2bf(a.z); r[3] = (short)f2bf(a.w);
    r[4] = (short)f2bf(b.x); r[5] = (short)f2bf(b.y);
    r[6] = (short)f2bf(b.z); r[7] = (short)f2bf(b.w);
    return r;
}

// ---------------- graph build: bucketed counting sort ----------------

// phase 0: bucket histogram (bucket = dst >> 6), LDS-aggregated
__global__ __launch_bounds__(256) void p0_hist(const int* __restrict__ dst,
                                               int* __restrict__ bhist, int E, int nbuck,
                                               int ch) {
    __shared__ int h[MAXBUCK];
    for (int i = threadIdx.x; i < nbuck; i += 256) h[i] = 0;
    __syncthreads();
    int base = blockIdx.x * ch;
    int lim = min(base + ch, E);
    for (int e = base + threadIdx.x; e < lim; e += 256) atomicAdd(&h[dst[e] >> 6], 1);
    __syncthreads();
    for (int i = threadIdx.x; i < nbuck; i += 256) {
        int v = h[i];
        if (v) atomicAdd(&bhist[i], v);
    }
}

// exclusive scan of bhist -> bstart (and gpos copy); sets sentinels
__global__ __launch_bounds__(256) void p_scan(const int* __restrict__ bhist,
                                              int* __restrict__ bstart,
                                              int* __restrict__ gpos, int nbuck,
                                              int* __restrict__ row_ptr, int N, int E) {
    __shared__ int ws[4];
    __shared__ int carry;
    int t = threadIdx.x, lane = t & 63, w = t >> 6;
    if (t == 0) carry = 0;
    __syncthreads();
    for (int base = 0; base < nbuck; base += 256) {
        int i = base + t;
        int v = (i < nbuck) ? bhist[i] : 0;
        int s = v;
        #pragma unroll
        for (int off = 1; off < 64; off <<= 1) {
            int u = __shfl_up(s, off);
            if (lane >= off) s += u;
        }
        if (lane == 63) ws[w] = s;
        __syncthreads();
        int pre = 0;
        #pragma unroll
        for (int j = 0; j < 4; ++j)
            if (j < w) pre += ws[j];
        int excl = carry + pre + s - v;
        if (i < nbuck) {
            bstart[i] = excl;
            gpos[i] = excl;
        }
        __syncthreads();
        if (t == 255) carry += pre + s;
        __syncthreads();
    }
    if (t == 0) {
        bstart[nbuck] = E;
        row_ptr[N] = E;
    }
}

// phase 1: scatter packed (src | dstlow<<17) into bucket regions; fold deg[src] atomics
__global__ __launch_bounds__(256) void p1_scatter(const int* __restrict__ src,
                                                  const int* __restrict__ dst,
                                                  int* __restrict__ gpos,
                                                  int* __restrict__ buf,
                                                  int* __restrict__ degi, int E, int nbuck,
                                                  int ch) {
    __shared__ int h[MAXBUCK];
    __shared__ int b[MAXBUCK];
    for (int i = threadIdx.x; i < nbuck; i += 256) h[i] = 0;
    __syncthreads();
    int base = blockIdx.x * ch;
    int lim = min(base + ch, E);
    for (int e = base + threadIdx.x; e < lim; e += 256) atomicAdd(&h[dst[e] >> 6], 1);
    __syncthreads();
    for (int i = threadIdx.x; i < nbuck; i += 256) {
        int v = h[i];
        b[i] = v ? atomicAdd(&gpos[i], v) : 0;
        h[i] = 0;
    }
    __syncthreads();
    for (int e = base + threadIdx.x; e < lim; e += 256) {
        int d = dst[e], s = src[e];
        int bk = d >> 6;
        int off = atomicAdd(&h[bk], 1);
        buf[b[bk] + off] = s | ((d & 63) << 17);
        atomicAdd(&degi[s], 1);
    }
}

// phase 2: per-bucket grouping into final CSR + row_ptr (all-LDS)
__global__ __launch_bounds__(256) void p2_group(const int* __restrict__ buf,
                                                const int* __restrict__ bstart,
                                                int* __restrict__ csr,
                                                int* __restrict__ row_ptr, int N) {
    int bk = blockIdx.x;
    int s0 = bstart[bk], s1 = bstart[bk + 1];
    __shared__ int cnt[64];
    __shared__ int pos[64];
    int t = threadIdx.x;
    if (t < 64) cnt[t] = 0;
    __syncthreads();
    for (int i = s0 + t; i < s1; i += 256) atomicAdd(&cnt[buf[i] >> 17], 1);
    __syncthreads();
    if (t < 64) {
        int v = cnt[t], s = v;
        #pragma unroll
        for (int off = 1; off < 64; off <<= 1) {
            int u = __shfl_up(s, off);
            if (t >= off) s += u;
        }
        int excl = s - v;
        int node = bk * 64 + t;
        if (node < N) row_ptr[node] = s0 + excl;
        pos[t] = s0 + excl;
    }
    __syncthreads();
    for (int i = s0 + t; i < s1; i += 256) {
        int p = buf[i];
        int off = atomicAdd(&pos[p >> 17], 1);
        csr[off] = p & 0x1FFFF;
    }
}

__global__ void k_dinv(const int* __restrict__ degi, float* __restrict__ dinv, int N) {
    int i = blockIdx.x * blockDim.x + threadIdx.x;
    if (i < N) {
        int d = degi[i];
        dinv[i] = (d > 0) ? rsqrtf((float)d) : 0.0f;
    }
}

// ---------------- Bernstein coefficients ----------------

__global__ void k_coef(const float* __restrict__ temp, float* __restrict__ c,
                       float* __restrict__ temp_out) {
    if (threadIdx.x != 0 || blockIdx.x != 0) return;
    float T[KORD + 1];
    #pragma unroll
    for (int j = 0; j <= KORD; ++j) {
        T[j] = fmaxf(temp[j], 0.0f);
        temp_out[j] = T[j];
    }
    float binom[KORD + 1][KORD + 1];
    for (int n = 0; n <= KORD; ++n) {
        binom[n][0] = 1.0f;
        for (int k = 1; k <= n; ++k)
            binom[n][k] = (k == n) ? 1.0f : binom[n - 1][k - 1] + binom[n - 1][k];
        for (int k = n + 1; k <= KORD; ++k) binom[n][k] = 0.0f;
    }
    for (int m = 0; m <= KORD; ++m) {
        float s = 0.0f;
        for (int j = 0; j <= KORD; ++j) {
            float cj = 0.0f;
            for (int p = 0; p <= j && p <= m; ++p) {
                int q = m - p;
                if (q > KORD - j) continue;
                float t = binom[j][p] * binom[KORD - j][q];
                cj += (p & 1) ? -t : t;
            }
            s += binom[KORD][j] * T[j] * cj;
        }
        c[m] = s * (1.0f / 1024.0f);
    }
}

// ---------------- weight prep: transpose + bf16 ----------------

__global__ void k_prepw(const float* __restrict__ W1, const float* __restrict__ W2,
                        ushort_t* __restrict__ W1t, ushort_t* __restrict__ W2t) {
    int id = blockIdx.x * blockDim.x + threadIdx.x;
    if (id < HIDDEN * NFEAT) {
        int n = id / NFEAT, k = id % NFEAT;
        W1t[id] = f2bf(W1[(size_t)k * HIDDEN + n]);
    } else if (id < HIDDEN * NFEAT + NCLASS * HIDDEN) {
        int j = id - HIDDEN * NFEAT;
        int n = j / HIDDEN, k = j % HIDDEN;
        W2t[j] = f2bf(W2[(size_t)k * NCLASS + n]);
    }
}

// ---------------- GEMM1: h1 = relu(x @ W1 + b1), bf16 MFMA ----------------

__global__ __launch_bounds__(256) void gemm1(const float* __restrict__ x,
                                             const ushort_t* __restrict__ W1t,
                                             const float* __restrict__ b1,
                                             ushort_t* __restrict__ h1, int M) {
    __shared__ char smem[24576];
    char* As = smem;
    char* Bs = smem + 8192;
    const int t = threadIdx.x;
    const int m0 = blockIdx.x * 64;
    const int wid = t >> 6, lane = t & 63;
    const int wr = wid >> 1, wc = wid & 1;
    const int lm = lane & 15, lg = lane >> 4;

    f32x4 acc[2][4];
    #pragma unroll
    for (int i = 0; i < 2; ++i)
        #pragma unroll
        for (int j = 0; j < 4; ++j) acc[i][j] = (f32x4){0.f, 0.f, 0.f, 0.f};

    for (int k0 = 0; k0 < NFEAT; k0 += 64) {
        #pragma unroll
        for (int i = 0; i < 2; ++i) {
            int idx = t + i * 256;
            int r = idx >> 3, c8 = idx & 7;
            float4 v0 = make_float4(0.f, 0.f, 0.f, 0.f), v1 = v0;
            if (m0 + r < M) {
                const float* p = &x[(size_t)(m0 + r) * NFEAT + k0 + c8 * 8];
                v0 = *(const float4*)p;
                v1 = *(const float4*)(p + 4);
            }
            *(short8*)(As + r * 128 + ((c8 * 16) ^ ((r & 7) << 4))) = pack8(v0, v1);
        }
        #pragma unroll
        for (int i = 0; i < 4; ++i) {
            int idx = t + i * 256;
            int r = idx >> 3, c8 = idx & 7;
            short8 v = *(const short8*)&W1t[(size_t)r * NFEAT + k0 + c8 * 8];
            *(short8*)(Bs + r * 128 + ((c8 * 16) ^ ((r & 7) << 4))) = v;
        }
        __syncthreads();
        #pragma unroll
        for (int kk = 0; kk < 64; kk += 32) {
            int kb = (kk + lg * 8) * 2;
            short8 af[2], bfr[4];
            #pragma unroll
            for (int fi = 0; fi < 2; ++fi) {
                int m = wr * 32 + fi * 16 + lm;
                af[fi] = *(const short8*)(As + m * 128 + (kb ^ ((m & 7) << 4)));
            }
            #pragma unroll
            for (int fj = 0; fj < 4; ++fj) {
                int n = wc * 64 + fj * 16 + lm;
                bfr[fj] = *(const short8*)(Bs + n * 128 + (kb ^ ((n & 7) << 4)));
            }
            #pragma unroll
            for (int fi = 0; fi < 2; ++fi)
                #pragma unroll
                for (int fj = 0; fj < 4; ++fj)
                    acc[fi][fj] = __builtin_amdgcn_mfma_f32_16x16x32_bf16(
                        af[fi], bfr[fj], acc[fi][fj], 0, 0, 0);
        }
        __syncthreads();
    }

    ushort_t* Cs = (ushort_t*)smem;
    #pragma unroll
    for (int fi = 0; fi < 2; ++fi)
        #pragma unroll
        for (int fj = 0; fj < 4; ++fj) {
            int col = wc * 64 + fj * 16 + lm;
            float bb = b1[col];
            #pragma unroll
            for (int q = 0; q < 4; ++q) {
                int r = wr * 32 + fi * 16 + lg * 4 + q;
                float z = fmaxf(acc[fi][fj][q] + bb, 0.0f);
                Cs[r * 128 + col] = f2bf(z);
            }
        }
    __syncthreads();
    #pragma unroll
    for (int i = 0; i < 4; ++i) {
        int idx = t + i * 256;
        int r = idx >> 4, c8 = idx & 15;
        if (m0 + r < M)
            *(short8*)&h1[(size_t)(m0 + r) * HIDDEN + c8 * 8] =
                *(const short8*)&Cs[r * 128 + c8 * 8];
    }
}

// ---------------- GEMM2: h = h1 @ W2 + b2 ; emits hb, g0 = bf16(dinv*cK*h) ----

__global__ __launch_bounds__(256) void gemm2(const ushort_t* __restrict__ h1,
                                             const ushort_t* __restrict__ W2t,
                                             const float* __restrict__ b2,
                                             const float* __restrict__ dinv,
                                             const float* __restrict__ c,
                                             ushort_t* __restrict__ hb,
                                             ushort_t* __restrict__ g0, int M) {
    __shared__ char smem[49152];
    char* As = smem;
    char* Bs = smem + 32768;
    const int t = threadIdx.x;
    const int m0 = blockIdx.x * 128;
    const int wr = t >> 6, lane = t & 63;
    const int lm = lane & 15, lg = lane >> 4;

    #pragma unroll
    for (int i = 0; i < 8; ++i) {
        int idx = t + i * 256;
        int r = idx >> 4, c8 = idx & 15;
        short8 v = (short8){0, 0, 0, 0, 0, 0, 0, 0};
        if (m0 + r < M) v = *(const short8*)&h1[(size_t)(m0 + r) * HIDDEN + c8 * 8];
        *(short8*)(As + r * 256 + ((c8 * 16) ^ ((r & 7) << 4))) = v;
    }
    #pragma unroll
    for (int i = 0; i < 4; ++i) {
        int idx = t + i * 256;
        int r = idx >> 4, c8 = idx & 15;
        short8 v = *(const short8*)&W2t[(size_t)r * HIDDEN + c8 * 8];
        *(short8*)(Bs + r * 256 + ((c8 * 16) ^ ((r & 7) << 4))) = v;
    }
    __syncthreads();

    f32x4 acc[2][4];
    #pragma unroll
    for (int i = 0; i < 2; ++i)
        #pragma unroll
        for (int j = 0; j < 4; ++j) acc[i][j] = (f32x4){0.f, 0.f, 0.f, 0.f};

    #pragma unroll
    for (int kk = 0; kk < HIDDEN; kk += 32) {
        int kb = (kk + lg * 8) * 2;
        short8 af[2], bfr[4];
        #pragma unroll
        for (int fi = 0; fi < 2; ++fi) {
            int m = wr * 32 + fi * 16 + lm;
            af[fi] = *(const short8*)(As + m * 256 + (kb ^ ((m & 7) << 4)));
        }
        #pragma unroll
        for (int fj = 0; fj < 4; ++fj) {
            int n = fj * 16 + lm;
            bfr[fj] = *(const short8*)(Bs + n * 256 + (kb ^ ((n & 7) << 4)));
        }
        #pragma unroll
        for (int fi = 0; fi < 2; ++fi)
            #pragma unroll
            for (int fj = 0; fj < 4; ++fj)
                acc[fi][fj] = __builtin_amdgcn_mfma_f32_16x16x32_bf16(
                    af[fi], bfr[fj], acc[fi][fj], 0, 0, 0);
    }

    float cK = c[KORD];
    #pragma unroll
    for (int fi = 0; fi < 2; ++fi)
        #pragma unroll
        for (int q = 0; q < 4; ++q) {
            int r = m0 + wr * 32 + fi * 16 + lg * 4 + q;
            if (r < M) {
                float dv = dinv[r];
                #pragma unroll
                for (int fj = 0; fj < 4; ++fj) {
                    int col = fj * 16 + lm;
                    float z = acc[fi][fj][q] + b2[col];
                    size_t o = (size_t)r * NCLASS + col;
                    hb[o] = f2bf(z);
                    g0[o] = f2bf(dv * cK * z);
                }
            }
        }
}

// ---------------- Horner SpMV step: w = A*w_prev + c[cidx]*h ----------------
// quad scheme: 4 edges per wave-load; 16 lanes per edge, ushort4 (4 features) per lane.

__global__ __launch_bounds__(256) void k_adj(const ushort_t* __restrict__ gin,
                                             const ushort_t* __restrict__ hb,
                                             const float* __restrict__ dinv,
                                             const int* __restrict__ row_ptr,
                                             const int* __restrict__ csr,
                                             const float* __restrict__ c, int cidx,
                                             ushort_t* __restrict__ gout,
                                             float* __restrict__ out, int last, int N) {
    int wid = blockIdx.x * 4 + (threadIdx.x >> 6);
    int lane = threadIdx.x & 63;
    if (wid >= N) return;
    const int g = lane >> 4;          // edge slot within quad
    const int f0 = (lane & 15) * 4;   // feature base
    int b = row_ptr[wid], e = row_ptr[wid + 1];

    float a0 = 0.f, a1 = 0.f, a2 = 0.f, a3 = 0.f;
    for (int i = b; i < e; i += 16) {
        #pragma unroll
        for (int u = 0; u < 4; ++u) {
            int ei = i + u * 4 + g;
            bool ok = ei < e;
            int s = ok ? csr[ei] : 0;
            us4v v = *(const us4v*)&gin[(size_t)s * NCLASS + f0];
            float m = ok ? 1.0f : 0.0f;
            a0 += m * bf2f(v[0]);
            a1 += m * bf2f(v[1]);
            a2 += m * bf2f(v[2]);
            a3 += m * bf2f(v[3]);
        }
    }
    // combine the 4 edge-groups
    #pragma unroll
    for (int off = 16; off <= 32; off <<= 1) {
        a0 += __shfl_xor(a0, off);
        a1 += __shfl_xor(a1, off);
        a2 += __shfl_xor(a2, off);
        a3 += __shfl_xor(a3, off);
    }

    float dv = dinv[wid];
    float cc = c[cidx];
    size_t o = (size_t)wid * NCLASS + f0;
    us4v hv = *(const us4v*)&hb[o];
    float w0 = dv * a0 + cc * bf2f(hv[0]);
    float w1 = dv * a1 + cc * bf2f(hv[1]);
    float w2 = dv * a2 + cc * bf2f(hv[2]);
    float w3 = dv * a3 + cc * bf2f(hv[3]);

    if (!last) {
        if (g == 0) {
            us4v r;
            r[0] = f2bf(dv * w0);
            r[1] = f2bf(dv * w1);
            r[2] = f2bf(dv * w2);
            r[3] = f2bf(dv * w3);
            *(us4v*)&gout[o] = r;
        }
    } else {
        float mx = fmaxf(fmaxf(w0, w1), fmaxf(w2, w3));
        #pragma unroll
        for (int off = 8; off >= 1; off >>= 1) mx = fmaxf(mx, __shfl_xor(mx, off));
        float s = expf(w0 - mx) + expf(w1 - mx) + expf(w2 - mx) + expf(w3 - mx);
        #pragma unroll
        for (int off = 8; off >= 1; off >>= 1) s += __shfl_xor(s, off);
        float ls = logf(s);
        if (g == 0) {
            float4 r = make_float4(w0 - mx - ls, w1 - mx - ls, w2 - mx - ls, w3 - mx - ls);
            *(float4*)&out[o] = r;
        }
    }
}

// ---------------- launch ----------------

extern "C" void kernel_launch(void* const* d_in, const int* in_sizes, int n_in,
                              void* d_out, int out_size, void* d_ws, size_t ws_size,
                              hipStream_t stream) {
    const float* x = (const float*)d_in[0];
    const int* ei = (const int*)d_in[1];
    const float* W1 = (const float*)d_in[2];
    const float* b1 = (const float*)d_in[3];
    const float* W2 = (const float*)d_in[4];
    const float* b2 = (const float*)d_in[5];
    const float* temp = (const float*)d_in[6];

    const int N = in_sizes[0] / NFEAT;  // 100000
    const int E = in_sizes[1] / 2;      // 3200000
    const int* src = ei;
    const int* dst = ei + E;
    const int nbuck = (N + 63) >> 6;    // 1563

    float* out = (float*)d_out;
    float* temp_out = out + (size_t)N * NCLASS;

    char* ws = (char*)d_ws;
    size_t off = 0;
    auto alloc = [&](size_t bytes) {
        char* p = ws + off;
        off = (off + bytes + 255) & ~(size_t)255;
        return p;
    };
    ushort_t* h1 = (ushort_t*)alloc((size_t)N * HIDDEN * sizeof(ushort_t));
    ushort_t* hb = (ushort_t*)alloc((size_t)N * NCLASS * sizeof(ushort_t));
    ushort_t* gA = (ushort_t*)alloc((size_t)N * NCLASS * sizeof(ushort_t));
    ushort_t* gB = (ushort_t*)alloc((size_t)N * NCLASS * sizeof(ushort_t));
    int* degi = (int*)alloc((size_t)N * sizeof(int));
    float* dinv = (float*)alloc((size_t)N * sizeof(float));
    int* row_ptr = (int*)alloc((size_t)(N + 1) * sizeof(int));
    int* bhist = (int*)alloc((size_t)MAXBUCK * sizeof(int));
    int* bstart = (int*)alloc((size_t)(MAXBUCK + 1) * sizeof(int));
    int* gpos = (int*)alloc((size_t)MAXBUCK * sizeof(int));
    int* csr = (int*)alloc((size_t)E * sizeof(int));
    ushort_t* W1t = (ushort_t*)alloc((size_t)HIDDEN * NFEAT * sizeof(ushort_t));
    ushort_t* W2t = (ushort_t*)alloc((size_t)NCLASS * HIDDEN * sizeof(ushort_t));
    float* c = (float*)alloc(64);
    (void)ws_size;

    int* buf = (int*)h1;  // bucket-scattered edges; dead before gemm1 writes h1

    const int TB = 256;
    const int ngrid = (N + TB - 1) / TB;
    const int ch = (E + NSCAT - 1) / NSCAT;  // 25000
    const int wgrid = (N + 3) / 4;

    hipMemsetAsync(degi, 0, (size_t)N * sizeof(int), stream);
    hipMemsetAsync(bhist, 0, (size_t)nbuck * sizeof(int), stream);
    p0_hist<<<NSCAT, TB, 0, stream>>>(dst, bhist, E, nbuck, ch);
    p_scan<<<1, TB, 0, stream>>>(bhist, bstart, gpos, nbuck, row_ptr, N, E);
    p1_scatter<<<NSCAT, TB, 0, stream>>>(src, dst, gpos, buf, degi, E, nbuck, ch);
    k_dinv<<<ngrid, TB, 0, stream>>>(degi, dinv, N);
    p2_group<<<nbuck, TB, 0, stream>>>(buf, bstart, csr, row_ptr, N);

    k_coef<<<1, 64, 0, stream>>>(temp, c, temp_out);
    k_prepw<<<(HIDDEN * NFEAT + NCLASS * HIDDEN + TB - 1) / TB, TB, 0, stream>>>(W1, W2, W1t, W2t);

    gemm1<<<(N + 63) / 64, TB, 0, stream>>>(x, W1t, b1, h1, N);
    gemm2<<<(N + 127) / 128, TB, 0, stream>>>(h1, W2t, b2, dinv, c, hb, gA, N);

    const ushort_t* gin = gA;
    ushort_t* gout = gB;
    for (int s = 1; s <= KORD; ++s) {
        int last = (s == KORD) ? 1 : 0;
        k_adj<<<wgrid, TB, 0, stream>>>(gin, hb, dinv, row_ptr, csr, c, KORD - s,
                                        gout, out, last, N);
        const ushort_t* tmp = gin;
        gin = gout;
        gout = (ushort_t*)tmp;
    }
}